// Round 10
// baseline (640.346 us; speedup 1.0000x reference)
//
#include <hip/hip_runtime.h>
#include <cstdint>

// ---------------------------------------------------------------------------
// GatedCrossAttention  (E=1024, Z=256, L=2048, B=8)
// Round 10: round-9 + transpose merged into the qk launch (tail-filling),
// workspace re-mapped so attn/vbce never overlap while concurrent.
//   S1 pre    = prep(LN+casts) + weight-cast
//   S2 fused3 = qru + k + v GEMMs (block-partitioned, K=1024)
//   S3 post   = l2norm(k,q) wave-per-row only
//   S4 qkT    = qk-GEMM (2048 blocks) + v-transpose (4096 blocks)
//   S5 h, S6 out GEMMs unchanged (128^2 engine).
// ---------------------------------------------------------------------------

#define EN 1024
#define ZN 256
#define LN_ 2048
#define BN_ 8
#define MROWS (LN_ * BN_)          // 16384
#define QRU_N (2 * EN + ZN)        // 2304
#define LEN_SCALE 0.022097086912079608f  // 1/sqrt(2048)

typedef unsigned short u16;
typedef __bf16 bf16x8 __attribute__((ext_vector_type(8)));
typedef float f32x4 __attribute__((ext_vector_type(4)));

// ---- bf16 helpers ---------------------------------------------------------
__device__ __forceinline__ u16 f2bf(float f) {
    unsigned int u = __float_as_uint(f);
    u = (u + 0x7fff + ((u >> 16) & 1)) >> 16;
    return (u16)u;
}
__device__ __forceinline__ float bf2f(u16 s) {
    return __uint_as_float(((unsigned int)s) << 16);
}
__device__ __forceinline__ void store_bf16x4(u16* p, float a, float b, float c, float d) {
    union { u16 h[4]; uint2 v; } pk;
    pk.h[0] = f2bf(a); pk.h[1] = f2bf(b); pk.h[2] = f2bf(c); pk.h[3] = f2bf(d);
    *(uint2*)p = pk.v;
}

// ---- async global->LDS (16B/lane, wave-uniform LDS base + lane*16) --------
__device__ __forceinline__ void async_load16(const void* g, void* l) {
    __builtin_amdgcn_global_load_lds(
        (const __attribute__((address_space(1))) void*)g,
        (__attribute__((address_space(3))) void*)l,
        16, 0, 0);
}

// ===========================================================================
// Shared 128x128 BK=64 engine body (m97 structure + XOR LDS swizzle).
// ===========================================================================
#define GEMM_CORE(Ab, Bb, m0, n0, K)                                             \
    for (int k0 = 0; k0 < (K); k0 += 64) {                                       \
        __syncthreads();                                                         \
        _Pragma("unroll")                                                        \
        for (int t = 0; t < 4; ++t) {                                            \
            const int rbase = w * 32 + t * 8;                                    \
            async_load16((Ab) + ((m0) + rbase + srow) * (K) + (k0 + scol),       \
                         (void*)&As[rbase * 64]);                                \
            async_load16((Bb) + ((n0) + rbase + srow) * (K) + (k0 + scol),       \
                         (void*)&Bs[rbase * 64]);                                \
        }                                                                        \
        __builtin_amdgcn_s_waitcnt(0);                                           \
        __syncthreads();                                                         \
        _Pragma("unroll")                                                        \
        for (int h = 0; h < 2; ++h) {                                            \
            const int ch = h ? choff1 : choff0;                                  \
            bf16x8 af[4], bfv[4];                                                \
            _Pragma("unroll")                                                    \
            for (int mi = 0; mi < 4; ++mi)                                       \
                af[mi] = *(const bf16x8*)&As[(wm * 64 + mi * 16 + l16) * 64 + ch];\
            _Pragma("unroll")                                                    \
            for (int ni = 0; ni < 4; ++ni)                                       \
                bfv[ni] = *(const bf16x8*)&Bs[(wn * 64 + ni * 16 + l16) * 64 + ch];\
            _Pragma("unroll")                                                    \
            for (int mi = 0; mi < 4; ++mi)                                       \
                _Pragma("unroll")                                                \
                for (int ni = 0; ni < 4; ++ni)                                   \
                    acc[mi][ni] = __builtin_amdgcn_mfma_f32_16x16x32_bf16(       \
                        af[mi], bfv[ni], acc[mi][ni], 0, 0, 0);                  \
        }                                                                        \
    }

#define GEMM_PREAMBLE()                                                          \
    const int tid  = threadIdx.x;                                                \
    const int lane = tid & 63;                                                   \
    const int w    = tid >> 6;                                                   \
    const int wm   = w >> 1, wn = w & 1;                                         \
    const int srow = lane >> 3;                                                  \
    const int scol = ((lane & 7) ^ srow) * 8;                                    \
    const int quad = lane >> 4;                                                  \
    const int l16  = lane & 15;                                                  \
    const int choff0 = ((quad     ^ (l16 & 7)) * 8);                             \
    const int choff1 = (((4 + quad) ^ (l16 & 7)) * 8);                           \
    const f32x4 fzero = {0.f, 0.f, 0.f, 0.f};                                    \
    f32x4 acc[4][4];                                                             \
    _Pragma("unroll")                                                            \
    for (int i = 0; i < 4; ++i)                                                  \
        _Pragma("unroll")                                                        \
        for (int j = 0; j < 4; ++j) acc[i][j] = fzero;

// ===========================================================================
// fused3: qru (blocks 0..2303), k (2304..2559), v (2560..3583).  All K=1024.
// ===========================================================================
__global__ __launch_bounds__(256, 4)
void gemm_fused3(const u16* __restrict__ nq, const u16* __restrict__ kin,
                 const u16* __restrict__ valb,
                 const u16* __restrict__ Wqru, const u16* __restrict__ Wk,
                 const u16* __restrict__ Wv,
                 float* __restrict__ qraw, u16* __restrict__ ub, u16* __restrict__ rb,
                 const float* __restrict__ bqru,
                 float* __restrict__ kraw, const float* __restrict__ bk,
                 u16* __restrict__ vbce, const float* __restrict__ bv)
{
    __shared__ __align__(16) u16 As[128 * 64];
    __shared__ __align__(16) u16 Bs[128 * 64];

    const int id = blockIdx.x;
    int seg, local, gx, nwg;
    const u16 *A, *B;
    if (id < 2304)      { seg = 0; local = id;        gx = 18; nwg = 2304; A = nq;   B = Wqru; }
    else if (id < 2560) { seg = 1; local = id - 2304; gx = 2;  nwg = 256;  A = kin;  B = Wk;  }
    else                { seg = 2; local = id - 2560; gx = 8;  nwg = 1024; A = valb; B = Wv;  }
    const int swz = (local & 7) * (nwg >> 3) + (local >> 3);
    const long long m0 = (long long)(swz / gx) * 128;
    const long long n0 = (long long)(swz % gx) * 128;

    GEMM_PREAMBLE();
    GEMM_CORE(A, B, m0, n0, 1024);

    // epilogue: D[row][col], col = lane&15, row = quad*4 + reg  [m89/m91]
    if (seg == 0) {
#pragma unroll
        for (int mi = 0; mi < 4; ++mi)
#pragma unroll
            for (int ni = 0; ni < 4; ++ni)
#pragma unroll
                for (int r = 0; r < 4; ++r) {
                    int m = (int)m0 + wm * 64 + mi * 16 + quad * 4 + r;
                    int n = (int)n0 + wn * 64 + ni * 16 + l16;
                    float v = acc[mi][ni][r] + bqru[n];
                    if (n < ZN) {
                        qraw[(long long)m * ZN + n] = v;
                    } else if (n < ZN + EN) {
                        float s = 1.f / (1.f + __expf(-v));
                        ub[(long long)m * EN + (n - ZN)] = f2bf(s);
                    } else {
                        float s = v / (1.f + __expf(-v));
                        rb[(long long)m * EN + (n - ZN - EN)] = f2bf(s);
                    }
                }
    } else if (seg == 1) {
#pragma unroll
        for (int mi = 0; mi < 4; ++mi)
#pragma unroll
            for (int ni = 0; ni < 4; ++ni)
#pragma unroll
                for (int r = 0; r < 4; ++r) {
                    int m = (int)m0 + wm * 64 + mi * 16 + quad * 4 + r;
                    int n = (int)n0 + wn * 64 + ni * 16 + l16;
                    kraw[(long long)m * ZN + n] = acc[mi][ni][r] + bk[n];
                }
    } else {
#pragma unroll
        for (int mi = 0; mi < 4; ++mi)
#pragma unroll
            for (int ni = 0; ni < 4; ++ni)
#pragma unroll
                for (int r = 0; r < 4; ++r) {
                    int m = (int)m0 + wm * 64 + mi * 16 + quad * 4 + r;
                    int n = (int)n0 + wn * 64 + ni * 16 + l16;
                    float x = acc[mi][ni][r] + bv[n];
                    float s = x / (1.f + __expf(-x));
                    int b = m & 7, c = m >> 3;
                    vbce[((long long)b * LN_ + c) * EN + n] = f2bf(s);
                }
    }
}

// ===========================================================================
// qkT: blocks [0,2048) = qk GEMM (K=256, per-batch 256-block T1 swizzle);
//      blocks [2048,6144) = v transpose (64x64 LDS tiles, aliased onto As).
// ===========================================================================
__global__ __launch_bounds__(256, 4)
void gemm_qk_trans(const u16* __restrict__ qb, const u16* __restrict__ kb,
                   u16* __restrict__ attn, const float* __restrict__ relpos,
                   const u16* __restrict__ vbce, u16* __restrict__ vT)
{
    __shared__ __align__(16) u16 As[128 * 64];
    __shared__ __align__(16) u16 Bs[128 * 64];

    const int id = blockIdx.x;
    if (id < 2048) {
        const int bz    = id >> 8;
        const int local = id & 255;
        const int swz   = (local & 7) * 32 + (local >> 3);   // nwg=256, bijective
        const long long m0 = (long long)(swz >> 4) * 128;    // gx = 16
        const long long n0 = (long long)(swz & 15) * 128;
        const u16* Ab = qb + (long long)bz * LN_ * ZN;
        const u16* Bb = kb + (long long)bz * LN_ * ZN;

        GEMM_PREAMBLE();
        GEMM_CORE(Ab, Bb, m0, n0, ZN);

#pragma unroll
        for (int mi = 0; mi < 4; ++mi)
#pragma unroll
            for (int ni = 0; ni < 4; ++ni)
#pragma unroll
                for (int r = 0; r < 4; ++r) {
                    int m = (int)m0 + wm * 64 + mi * 16 + quad * 4 + r;
                    int n = (int)n0 + wn * 64 + ni * 16 + l16;
                    float val = acc[mi][ni][r] * LEN_SCALE + relpos[2047 + n - m];
                    float t = fmaxf(val, 0.f);
                    attn[(long long)bz * LN_ * LN_ + (long long)m * LN_ + n] = f2bf(t * t);
                }
    } else {
        // transpose branch; tile aliased onto As (64*65*2 B = 8.3 KB <= 16 KB)
        u16 (*tile)[65] = (u16 (*)[65])As;
        const int id2 = id - 2048;             // [0, 4096)
        const int b  = id2 >> 9;               // 512 tiles per batch
        const int rem = id2 & 511;
        const int e0 = (rem & 15) * 64, c0 = (rem >> 4) * 64;
        const int t  = threadIdx.x;
        const int rc = t >> 3;                 // 0..31
        const int ec = t & 7;                  // 0..7
        const u16* src = vbce + (long long)b * LN_ * EN;
        u16* dst = vT + (long long)b * EN * LN_;
#pragma unroll
        for (int i = 0; i < 64; i += 32) {
            union { uint4 v4; u16 h[8]; } ld;
            ld.v4 = *(const uint4*)(src + (long long)(c0 + rc + i) * EN + (e0 + ec * 8));
#pragma unroll
            for (int j = 0; j < 8; ++j) tile[rc + i][ec * 8 + j] = ld.h[j];
        }
        __syncthreads();
#pragma unroll
        for (int i = 0; i < 64; i += 32) {
            union { uint4 v4; u16 h[8]; } st;
#pragma unroll
            for (int j = 0; j < 8; ++j) st.h[j] = tile[ec * 8 + j][rc + i];
            *(uint4*)(dst + (long long)(e0 + rc + i) * LN_ + (c0 + ec * 8)) = st.v4;
        }
    }
}

// ===========================================================================
// standalone 128^2 engine (h / out GEMMs)
// ===========================================================================
template <typename Epi>
__global__ __launch_bounds__(256, 4)
void gemm_bt(const u16* __restrict__ A, const u16* __restrict__ B,
             long long batchStrideA, long long batchStrideB, int K, Epi epi)
{
    __shared__ __align__(16) u16 As[128 * 64];
    __shared__ __align__(16) u16 Bs[128 * 64];

    const int bz   = blockIdx.z;
    const int gx   = gridDim.x;
    const int nwg  = gx * gridDim.y;
    const int orig = blockIdx.y * gx + blockIdx.x;
    const int swz  = ((nwg & 7) == 0) ? ((orig & 7) * (nwg >> 3) + (orig >> 3)) : orig;
    const long long m0 = (long long)(swz / gx) * 128;
    const long long n0 = (long long)(swz % gx) * 128;

    const u16* Ab = A + bz * batchStrideA;
    const u16* Bb = B + bz * batchStrideB;

    GEMM_PREAMBLE();
    GEMM_CORE(Ab, Bb, m0, n0, K);

#pragma unroll
    for (int mi = 0; mi < 4; ++mi)
#pragma unroll
        for (int ni = 0; ni < 4; ++ni)
#pragma unroll
            for (int r = 0; r < 4; ++r) {
                int m = (int)m0 + wm * 64 + mi * 16 + quad * 4 + r;
                int n = (int)n0 + wn * 64 + ni * 16 + l16;
                epi(bz, m, n, acc[mi][ni][r]);
            }
}

// ---- epilogue functors for the remaining GEMMs ------------------------------
struct EpiH {              // hr = (attn@v) * r, bf16 rows (s*8+b)
    u16* hr; const u16* r;
    __device__ void operator()(int bz, int m, int n, float acc) const {
        long long idx = ((long long)m * BN_ + bz) * EN + n;
        hr[idx] = f2bf(acc * bf2f(r[idx]));
    }
};
struct EpiOut {            // out = query + u*((hr@Wh^T + bh) - query), fp32
    float* out; const float* query; const u16* u; const float* bh;
    __device__ void operator()(int, int m, int n, float acc) const {
        long long idx = (long long)m * EN + n;
        float qv = query[idx];
        float uu = bf2f(u[idx]);
        out[idx] = qv + uu * ((acc + bh[n]) - qv);
    }
};

// ---------------------------------------------------------------------------
// pre: blocks [0, MROWS/4) = prep (wave-per-row LN + casts);
//      blocks [MROWS/4, ..) = weight cast (grid-strided segments).
// ---------------------------------------------------------------------------
#define N4_QRU (QRU_N * EN / 4)            // 589824
#define N4_K   (ZN * EN / 4)               // 65536
#define N4_V   (EN * EN / 4)               // 262144
#define N4_H   (EN * EN / 4)               // 262144
#define N4_TOT (N4_QRU + N4_K + N4_V + N4_H)   // 1179648 = 4608 * 256
#define PREP_BLKS (MROWS / 4)              // 4096
#define CAST_BLKS (N4_TOT / 256)           // 4608

__global__ __launch_bounds__(256)
void pre_kernel(const float* __restrict__ query, const float* __restrict__ key_in,
                const float* __restrict__ value, const float* __restrict__ ln_w,
                const float* __restrict__ ln_b,
                u16* __restrict__ nq, u16* __restrict__ kin, u16* __restrict__ val,
                const float* __restrict__ Wqru, const float* __restrict__ Wk,
                const float* __restrict__ Wv,   const float* __restrict__ Wh,
                u16* __restrict__ dQru, u16* __restrict__ dK,
                u16* __restrict__ dV,   u16* __restrict__ dH)
{
    const int id = blockIdx.x;
    if (id < PREP_BLKS) {
        const int w = threadIdx.x >> 6, lane = threadIdx.x & 63;
        const int m = id * 4 + w;
        const long long rowb = (long long)m * EN;
        float4 q[4];
        float a1 = 0.f, a2 = 0.f;
#pragma unroll
        for (int p = 0; p < 4; ++p) {
            q[p] = *(const float4*)(query + rowb + p * 256 + lane * 4);
            a1 += q[p].x + q[p].y + q[p].z + q[p].w;
            a2 += q[p].x * q[p].x + q[p].y * q[p].y + q[p].z * q[p].z + q[p].w * q[p].w;
        }
#pragma unroll
        for (int o = 32; o; o >>= 1) { a1 += __shfl_down(a1, o, 64); a2 += __shfl_down(a2, o, 64); }
        const float S1 = __shfl(a1, 0, 64);
        const float S2 = __shfl(a2, 0, 64);
        const float mu = S1 * (1.f / EN);
        const float var = S2 * (1.f / EN) - mu * mu;
        const float rstd = rsqrtf(var + 1e-5f);
#pragma unroll
        for (int p = 0; p < 4; ++p) {
            const long long off = rowb + p * 256 + lane * 4;
            const int e = p * 256 + lane * 4;
            float4 wv = *(const float4*)(ln_w + e);
            float4 bvv = *(const float4*)(ln_b + e);
            store_bf16x4(nq + off,
                         (q[p].x - mu) * rstd * wv.x + bvv.x, (q[p].y - mu) * rstd * wv.y + bvv.y,
                         (q[p].z - mu) * rstd * wv.z + bvv.z, (q[p].w - mu) * rstd * wv.w + bvv.w);
            float4 kq = *(const float4*)(key_in + off);
            store_bf16x4(kin + off, kq.x, kq.y, kq.z, kq.w);
            float4 vq = *(const float4*)(value + off);
            store_bf16x4(val + off, vq.x, vq.y, vq.z, vq.w);
        }
    } else {
        int i = (id - PREP_BLKS) * 256 + threadIdx.x;
        const float* src; u16* dst; int j = i;
        if (j < N4_QRU)                { src = Wqru; dst = dQru; }
        else if ((j -= N4_QRU) < N4_K) { src = Wk;   dst = dK;   }
        else if ((j -= N4_K) < N4_V)   { src = Wv;   dst = dV;   }
        else { j -= N4_V;                src = Wh;   dst = dH;   }
        float4 x = ((const float4*)src)[j];
        store_bf16x4(dst + (long long)j * 4, x.x, x.y, x.z, x.w);
    }
}

// ---------------------------------------------------------------------------
// post: l2norm wave-per-row only (k rows then q rows); 4 rows/block.
// ---------------------------------------------------------------------------
#define L2_BLKS (2 * MROWS / 4)             // 8192

__global__ __launch_bounds__(256)
void post_kernel(const float* __restrict__ kraw, const float* __restrict__ qraw,
                 u16* __restrict__ kb, u16* __restrict__ qb,
                 const float* __restrict__ gamma, const float* __restrict__ beta)
{
    const int w = threadIdx.x >> 6, lane = threadIdx.x & 63;
    const int gm = blockIdx.x * 4 + w;     // 0..32767
    const int which = gm >> 14;            // 0 = k, 1 = q
    const int m = gm & (MROWS - 1);
    const float* raw = which ? qraw : kraw;
    u16* outp = which ? qb : kb;
    const float* g = gamma + (which ? 0 : ZN);
    const float* be = beta + (which ? 0 : ZN);

    float4 x = *(const float4*)(raw + (long long)m * ZN + lane * 4);
    float ss = x.x * x.x + x.y * x.y + x.z * x.z + x.w * x.w;
#pragma unroll
    for (int o = 32; o; o >>= 1) ss += __shfl_down(ss, o, 64);
    const float tot = __shfl(ss, 0, 64);
    const float inv = 1.f / fmaxf(sqrtf(tot), 1e-5f);
    float4 gv = *(const float4*)(g + lane * 4);
    float4 bv = *(const float4*)(be + lane * 4);
    const int b = m & 7, s = m >> 3;
    store_bf16x4(outp + ((long long)b * LN_ + s) * ZN + lane * 4,
                 x.x * inv * (gv.x + 1.f) + bv.x, x.y * inv * (gv.y + 1.f) + bv.y,
                 x.z * inv * (gv.z + 1.f) + bv.z, x.w * inv * (gv.w + 1.f) + bv.w);
}

// ---------------------------------------------------------------------------
extern "C" void kernel_launch(void* const* d_in, const int* in_sizes, int n_in,
                              void* d_out, int out_size, void* d_ws, size_t ws_size,
                              hipStream_t stream)
{
    const float* query  = (const float*)d_in[0];
    const float* key_in = (const float*)d_in[1];
    const float* value  = (const float*)d_in[2];
    const float* ln_w   = (const float*)d_in[3];
    const float* ln_b   = (const float*)d_in[4];
    const float* Wv     = (const float*)d_in[5];
    const float* bv     = (const float*)d_in[6];
    const float* Wk     = (const float*)d_in[7];
    const float* bk     = (const float*)d_in[8];
    const float* Wqru   = (const float*)d_in[9];
    const float* bqru   = (const float*)d_in[10];
    const float* Wh     = (const float*)d_in[11];
    const float* bh     = (const float*)d_in[12];
    const float* gamma  = (const float*)d_in[13];
    const float* beta   = (const float*)d_in[14];
    const float* relpos = (const float*)d_in[15];
    float* out = (float*)d_out;

    char* ws = (char*)d_ws;
    const size_t MB = 1ull << 20;
    // ---- lifetimes: S1 pre, S2 fused3, S3 post, S4 qkT, S5 h, S6 out ----
    // S1->S2: nq(0-32) kin(32-64) valb(64-96); WqruB/WkB/WvB(224-232) WhB->S6(232-234)
    // S2->S3: qraw(96-112) kraw(112-128)
    // S2->S4: vbce(128-160)   [transpose reads it inside S4]
    // S2->S6: ub(160-192)     S2->S5: rb(192-224)
    // S3->S4: qb(32-40) kb(40-48)         [over dead kin]
    // S4->S5: vT(0-32, over dead nq); attn(48-112, over dead kin-hi/valb/qraw)
    // S5->S6: hr(128-160, over dead vbce)
    u16*   nq    = (u16*)(ws + 0);
    u16*   kin   = (u16*)(ws + 32 * MB);
    u16*   valb  = (u16*)(ws + 64 * MB);
    float* qraw  = (float*)(ws + 96 * MB);
    float* kraw  = (float*)(ws + 112 * MB);
    u16*   vbce  = (u16*)(ws + 128 * MB);
    u16*   ub    = (u16*)(ws + 160 * MB);
    u16*   rb    = (u16*)(ws + 192 * MB);
    u16*   WqruB = (u16*)(ws + 224 * MB);   // 4.5 MiB
    u16*   WkB   = (u16*)(ws + 229 * MB);   // 0.5 MiB
    u16*   WvB   = (u16*)(ws + 230 * MB);   // 2 MiB
    u16*   WhB   = (u16*)(ws + 232 * MB);   // 2 MiB
    u16*   vT    = (u16*)(ws + 0);          // 32 MiB
    u16*   qb    = (u16*)(ws + 32 * MB);    // 8 MiB
    u16*   kb    = (u16*)(ws + 40 * MB);    // 8 MiB
    u16*   attn  = (u16*)(ws + 48 * MB);    // 64 MiB
    u16*   hr    = (u16*)(ws + 128 * MB);   // 32 MiB
    (void)ws_size; (void)in_sizes; (void)n_in; (void)out_size;

    // S1) prep + weight casts
    pre_kernel<<<dim3(PREP_BLKS + CAST_BLKS), 256, 0, stream>>>(
        query, key_in, value, ln_w, ln_b, nq, kin, valb,
        Wqru, Wk, Wv, Wh, WqruB, WkB, WvB, WhB);

    // S2) fused qru + k + v GEMMs (all K = 1024)
    gemm_fused3<<<dim3(2304 + 256 + 1024), 256, 0, stream>>>(
        nq, kin, valb, WqruB, WkB, WvB,
        qraw, ub, rb, bqru, kraw, bk, vbce, bv);

    // S3) l2norm (k and q, wave-per-row)
    post_kernel<<<dim3(L2_BLKS), 256, 0, stream>>>(
        kraw, qraw, kb, qb, gamma, beta);

    // S4) attn = relu(q@k^T*scale+bias)^2  +  v transpose (tail-filling)
    gemm_qk_trans<<<dim3(2048 + 4096), 256, 0, stream>>>(
        qb, kb, attn, relpos, vbce, vT);

    // S5) hr = (attn @ v) * r   (batched over b, K=2048)
    gemm_bt<<<dim3(EN / 128, LN_ / 128, BN_), 256, 0, stream>>>(
        attn, vT, (long long)LN_ * LN_, (long long)EN * LN_, LN_, EpiH{hr, rb});

    // S6) out = query + u*((hr@Wh^T + bh) - query)
    gemm_bt<<<dim3(EN / 128, MROWS / 128, 1), 256, 0, stream>>>(
        hr, WhB, 0LL, 0LL, EN, EpiOut{out, query, ub, bh});
}

// Round 11
// 602.862 us; speedup vs baseline: 1.0622x; 1.0622x over previous
//
#include <hip/hip_runtime.h>
#include <cstdint>

// ---------------------------------------------------------------------------
// GatedCrossAttention  (E=1024, Z=256, L=2048, B=8)
// Round 11: exact revert to round 9 (best verified, 608.8 us).
//   pre    = prep(LN+casts) + weight-cast           (1 launch)
//   fused3 = qru-GEMM + k-GEMM + v-GEMM (all K=1024, block-partitioned)
//   post   = l2norm(k,q) [wave-per-row, float4] + transpose(v)
//   qk, h, out GEMMs on the 128^2 m97-style engine + T1 XCD swizzle.
// Round-10 lesson: do NOT merge the BW-bound transpose into the qk launch
// (cross-regime tail-filling regressed -32 us); keep it with l2norm.
// ---------------------------------------------------------------------------

#define EN 1024
#define ZN 256
#define LN_ 2048
#define BN_ 8
#define MROWS (LN_ * BN_)          // 16384
#define QRU_N (2 * EN + ZN)        // 2304
#define LEN_SCALE 0.022097086912079608f  // 1/sqrt(2048)

typedef unsigned short u16;
typedef __bf16 bf16x8 __attribute__((ext_vector_type(8)));
typedef float f32x4 __attribute__((ext_vector_type(4)));

// ---- bf16 helpers ---------------------------------------------------------
__device__ __forceinline__ u16 f2bf(float f) {
    unsigned int u = __float_as_uint(f);
    u = (u + 0x7fff + ((u >> 16) & 1)) >> 16;
    return (u16)u;
}
__device__ __forceinline__ float bf2f(u16 s) {
    return __uint_as_float(((unsigned int)s) << 16);
}
__device__ __forceinline__ void store_bf16x4(u16* p, float a, float b, float c, float d) {
    union { u16 h[4]; uint2 v; } pk;
    pk.h[0] = f2bf(a); pk.h[1] = f2bf(b); pk.h[2] = f2bf(c); pk.h[3] = f2bf(d);
    *(uint2*)p = pk.v;
}

// ---- async global->LDS (16B/lane, wave-uniform LDS base + lane*16) --------
__device__ __forceinline__ void async_load16(const void* g, void* l) {
    __builtin_amdgcn_global_load_lds(
        (const __attribute__((address_space(1))) void*)g,
        (__attribute__((address_space(3))) void*)l,
        16, 0, 0);
}

// ===========================================================================
// Shared 128x128 BK=64 engine body (m97 structure + XOR LDS swizzle).
// ===========================================================================
#define GEMM_CORE(Ab, Bb, m0, n0, K)                                             \
    for (int k0 = 0; k0 < (K); k0 += 64) {                                       \
        __syncthreads();                                                         \
        _Pragma("unroll")                                                        \
        for (int t = 0; t < 4; ++t) {                                            \
            const int rbase = w * 32 + t * 8;                                    \
            async_load16((Ab) + ((m0) + rbase + srow) * (K) + (k0 + scol),       \
                         (void*)&As[rbase * 64]);                                \
            async_load16((Bb) + ((n0) + rbase + srow) * (K) + (k0 + scol),       \
                         (void*)&Bs[rbase * 64]);                                \
        }                                                                        \
        __builtin_amdgcn_s_waitcnt(0);                                           \
        __syncthreads();                                                         \
        _Pragma("unroll")                                                        \
        for (int h = 0; h < 2; ++h) {                                            \
            const int ch = h ? choff1 : choff0;                                  \
            bf16x8 af[4], bfv[4];                                                \
            _Pragma("unroll")                                                    \
            for (int mi = 0; mi < 4; ++mi)                                       \
                af[mi] = *(const bf16x8*)&As[(wm * 64 + mi * 16 + l16) * 64 + ch];\
            _Pragma("unroll")                                                    \
            for (int ni = 0; ni < 4; ++ni)                                       \
                bfv[ni] = *(const bf16x8*)&Bs[(wn * 64 + ni * 16 + l16) * 64 + ch];\
            _Pragma("unroll")                                                    \
            for (int mi = 0; mi < 4; ++mi)                                       \
                _Pragma("unroll")                                                \
                for (int ni = 0; ni < 4; ++ni)                                   \
                    acc[mi][ni] = __builtin_amdgcn_mfma_f32_16x16x32_bf16(       \
                        af[mi], bfv[ni], acc[mi][ni], 0, 0, 0);                  \
        }                                                                        \
    }

#define GEMM_PREAMBLE()                                                          \
    const int tid  = threadIdx.x;                                                \
    const int lane = tid & 63;                                                   \
    const int w    = tid >> 6;                                                   \
    const int wm   = w >> 1, wn = w & 1;                                         \
    const int srow = lane >> 3;                                                  \
    const int scol = ((lane & 7) ^ srow) * 8;                                    \
    const int quad = lane >> 4;                                                  \
    const int l16  = lane & 15;                                                  \
    const int choff0 = ((quad     ^ (l16 & 7)) * 8);                             \
    const int choff1 = (((4 + quad) ^ (l16 & 7)) * 8);                           \
    const f32x4 fzero = {0.f, 0.f, 0.f, 0.f};                                    \
    f32x4 acc[4][4];                                                             \
    _Pragma("unroll")                                                            \
    for (int i = 0; i < 4; ++i)                                                  \
        _Pragma("unroll")                                                        \
        for (int j = 0; j < 4; ++j) acc[i][j] = fzero;

// ===========================================================================
// fused3: qru (blocks 0..2303), k (2304..2559), v (2560..3583).  All K=1024.
// ===========================================================================
__global__ __launch_bounds__(256, 4)
void gemm_fused3(const u16* __restrict__ nq, const u16* __restrict__ kin,
                 const u16* __restrict__ valb,
                 const u16* __restrict__ Wqru, const u16* __restrict__ Wk,
                 const u16* __restrict__ Wv,
                 float* __restrict__ qraw, u16* __restrict__ ub, u16* __restrict__ rb,
                 const float* __restrict__ bqru,
                 float* __restrict__ kraw, const float* __restrict__ bk,
                 u16* __restrict__ vbce, const float* __restrict__ bv)
{
    __shared__ __align__(16) u16 As[128 * 64];
    __shared__ __align__(16) u16 Bs[128 * 64];

    const int id = blockIdx.x;
    int seg, local, gx, nwg;
    const u16 *A, *B;
    if (id < 2304)      { seg = 0; local = id;        gx = 18; nwg = 2304; A = nq;   B = Wqru; }
    else if (id < 2560) { seg = 1; local = id - 2304; gx = 2;  nwg = 256;  A = kin;  B = Wk;  }
    else                { seg = 2; local = id - 2560; gx = 8;  nwg = 1024; A = valb; B = Wv;  }
    const int swz = (local & 7) * (nwg >> 3) + (local >> 3);
    const long long m0 = (long long)(swz / gx) * 128;
    const long long n0 = (long long)(swz % gx) * 128;

    GEMM_PREAMBLE();
    GEMM_CORE(A, B, m0, n0, 1024);

    // epilogue: D[row][col], col = lane&15, row = quad*4 + reg  [m89/m91]
    if (seg == 0) {
#pragma unroll
        for (int mi = 0; mi < 4; ++mi)
#pragma unroll
            for (int ni = 0; ni < 4; ++ni)
#pragma unroll
                for (int r = 0; r < 4; ++r) {
                    int m = (int)m0 + wm * 64 + mi * 16 + quad * 4 + r;
                    int n = (int)n0 + wn * 64 + ni * 16 + l16;
                    float v = acc[mi][ni][r] + bqru[n];
                    if (n < ZN) {
                        qraw[(long long)m * ZN + n] = v;
                    } else if (n < ZN + EN) {
                        float s = 1.f / (1.f + __expf(-v));
                        ub[(long long)m * EN + (n - ZN)] = f2bf(s);
                    } else {
                        float s = v / (1.f + __expf(-v));
                        rb[(long long)m * EN + (n - ZN - EN)] = f2bf(s);
                    }
                }
    } else if (seg == 1) {
#pragma unroll
        for (int mi = 0; mi < 4; ++mi)
#pragma unroll
            for (int ni = 0; ni < 4; ++ni)
#pragma unroll
                for (int r = 0; r < 4; ++r) {
                    int m = (int)m0 + wm * 64 + mi * 16 + quad * 4 + r;
                    int n = (int)n0 + wn * 64 + ni * 16 + l16;
                    kraw[(long long)m * ZN + n] = acc[mi][ni][r] + bk[n];
                }
    } else {
#pragma unroll
        for (int mi = 0; mi < 4; ++mi)
#pragma unroll
            for (int ni = 0; ni < 4; ++ni)
#pragma unroll
                for (int r = 0; r < 4; ++r) {
                    int m = (int)m0 + wm * 64 + mi * 16 + quad * 4 + r;
                    int n = (int)n0 + wn * 64 + ni * 16 + l16;
                    float x = acc[mi][ni][r] + bv[n];
                    float s = x / (1.f + __expf(-x));
                    int b = m & 7, c = m >> 3;
                    vbce[((long long)b * LN_ + c) * EN + n] = f2bf(s);
                }
    }
}

// ===========================================================================
// standalone 128^2 engine (qk / h / out GEMMs)
// ===========================================================================
template <typename Epi>
__global__ __launch_bounds__(256, 4)
void gemm_bt(const u16* __restrict__ A, const u16* __restrict__ B,
             long long batchStrideA, long long batchStrideB, int K, Epi epi)
{
    __shared__ __align__(16) u16 As[128 * 64];
    __shared__ __align__(16) u16 Bs[128 * 64];

    const int bz   = blockIdx.z;
    const int gx   = gridDim.x;
    const int nwg  = gx * gridDim.y;
    const int orig = blockIdx.y * gx + blockIdx.x;
    const int swz  = ((nwg & 7) == 0) ? ((orig & 7) * (nwg >> 3) + (orig >> 3)) : orig;
    const long long m0 = (long long)(swz / gx) * 128;
    const long long n0 = (long long)(swz % gx) * 128;

    const u16* Ab = A + bz * batchStrideA;
    const u16* Bb = B + bz * batchStrideB;

    GEMM_PREAMBLE();
    GEMM_CORE(Ab, Bb, m0, n0, K);

#pragma unroll
    for (int mi = 0; mi < 4; ++mi)
#pragma unroll
        for (int ni = 0; ni < 4; ++ni)
#pragma unroll
            for (int r = 0; r < 4; ++r) {
                int m = (int)m0 + wm * 64 + mi * 16 + quad * 4 + r;
                int n = (int)n0 + wn * 64 + ni * 16 + l16;
                epi(bz, m, n, acc[mi][ni][r]);
            }
}

// ---- epilogue functors for the remaining GEMMs ------------------------------
struct EpiQK {             // attn = relu(qk*scale + bias)^2, bf16 (b, s, c)
    u16* attn; const float* relpos;
    __device__ void operator()(int bz, int m, int n, float v) const {
        float val = v * LEN_SCALE + relpos[2047 + n - m];
        float t = fmaxf(val, 0.f);
        attn[(long long)bz * LN_ * LN_ + (long long)m * LN_ + n] = f2bf(t * t);
    }
};
struct EpiH {              // hr = (attn@v) * r, bf16 rows (s*8+b)
    u16* hr; const u16* r;
    __device__ void operator()(int bz, int m, int n, float acc) const {
        long long idx = ((long long)m * BN_ + bz) * EN + n;
        hr[idx] = f2bf(acc * bf2f(r[idx]));
    }
};
struct EpiOut {            // out = query + u*((hr@Wh^T + bh) - query), fp32
    float* out; const float* query; const u16* u; const float* bh;
    __device__ void operator()(int, int m, int n, float acc) const {
        long long idx = (long long)m * EN + n;
        float qv = query[idx];
        float uu = bf2f(u[idx]);
        out[idx] = qv + uu * ((acc + bh[n]) - qv);
    }
};

// ---------------------------------------------------------------------------
// pre: blocks [0, MROWS/4) = prep (wave-per-row LN + casts);
//      blocks [MROWS/4, ..) = weight cast (grid-strided segments).
// ---------------------------------------------------------------------------
#define N4_QRU (QRU_N * EN / 4)            // 589824
#define N4_K   (ZN * EN / 4)               // 65536
#define N4_V   (EN * EN / 4)               // 262144
#define N4_H   (EN * EN / 4)               // 262144
#define N4_TOT (N4_QRU + N4_K + N4_V + N4_H)   // 1179648 = 4608 * 256
#define PREP_BLKS (MROWS / 4)              // 4096
#define CAST_BLKS (N4_TOT / 256)           // 4608

__global__ __launch_bounds__(256)
void pre_kernel(const float* __restrict__ query, const float* __restrict__ key_in,
                const float* __restrict__ value, const float* __restrict__ ln_w,
                const float* __restrict__ ln_b,
                u16* __restrict__ nq, u16* __restrict__ kin, u16* __restrict__ val,
                const float* __restrict__ Wqru, const float* __restrict__ Wk,
                const float* __restrict__ Wv,   const float* __restrict__ Wh,
                u16* __restrict__ dQru, u16* __restrict__ dK,
                u16* __restrict__ dV,   u16* __restrict__ dH)
{
    const int id = blockIdx.x;
    if (id < PREP_BLKS) {
        const int w = threadIdx.x >> 6, lane = threadIdx.x & 63;
        const int m = id * 4 + w;
        const long long rowb = (long long)m * EN;
        float4 q[4];
        float a1 = 0.f, a2 = 0.f;
#pragma unroll
        for (int p = 0; p < 4; ++p) {
            q[p] = *(const float4*)(query + rowb + p * 256 + lane * 4);
            a1 += q[p].x + q[p].y + q[p].z + q[p].w;
            a2 += q[p].x * q[p].x + q[p].y * q[p].y + q[p].z * q[p].z + q[p].w * q[p].w;
        }
#pragma unroll
        for (int o = 32; o; o >>= 1) { a1 += __shfl_down(a1, o, 64); a2 += __shfl_down(a2, o, 64); }
        const float S1 = __shfl(a1, 0, 64);
        const float S2 = __shfl(a2, 0, 64);
        const float mu = S1 * (1.f / EN);
        const float var = S2 * (1.f / EN) - mu * mu;
        const float rstd = rsqrtf(var + 1e-5f);
#pragma unroll
        for (int p = 0; p < 4; ++p) {
            const long long off = rowb + p * 256 + lane * 4;
            const int e = p * 256 + lane * 4;
            float4 wv = *(const float4*)(ln_w + e);
            float4 bvv = *(const float4*)(ln_b + e);
            store_bf16x4(nq + off,
                         (q[p].x - mu) * rstd * wv.x + bvv.x, (q[p].y - mu) * rstd * wv.y + bvv.y,
                         (q[p].z - mu) * rstd * wv.z + bvv.z, (q[p].w - mu) * rstd * wv.w + bvv.w);
            float4 kq = *(const float4*)(key_in + off);
            store_bf16x4(kin + off, kq.x, kq.y, kq.z, kq.w);
            float4 vq = *(const float4*)(value + off);
            store_bf16x4(val + off, vq.x, vq.y, vq.z, vq.w);
        }
    } else {
        int i = (id - PREP_BLKS) * 256 + threadIdx.x;
        const float* src; u16* dst; int j = i;
        if (j < N4_QRU)                { src = Wqru; dst = dQru; }
        else if ((j -= N4_QRU) < N4_K) { src = Wk;   dst = dK;   }
        else if ((j -= N4_K) < N4_V)   { src = Wv;   dst = dV;   }
        else { j -= N4_V;                src = Wh;   dst = dH;   }
        float4 x = ((const float4*)src)[j];
        store_bf16x4(dst + (long long)j * 4, x.x, x.y, x.z, x.w);
    }
}

// ---------------------------------------------------------------------------
// post: blocks [0, 8192) = l2norm wave-per-row (k rows then q rows);
//       blocks [8192, 12288) = transpose v->vT (64x64 LDS tiles, 16B both ways)
// ---------------------------------------------------------------------------
#define L2_BLKS (2 * MROWS / 4)             // 8192  (4 rows per block)
#define TR_BLKS (BN_ * (LN_ / 64) * (EN / 64))  // 4096

__global__ __launch_bounds__(256)
void post_kernel(const float* __restrict__ kraw, const float* __restrict__ qraw,
                 u16* __restrict__ kb, u16* __restrict__ qb,
                 const float* __restrict__ gamma, const float* __restrict__ beta,
                 const u16* __restrict__ vbce, u16* __restrict__ vT)
{
    __shared__ u16 tile[64][65];           // used only by transpose branch
    const int id = blockIdx.x;
    if (id < L2_BLKS) {
        // wave-per-row l2norm: row = id*4 + wave; Z=256 = 64 lanes x float4
        const int w = threadIdx.x >> 6, lane = threadIdx.x & 63;
        const int gm = id * 4 + w;             // 0..32767
        const int which = gm >> 14;            // 0 = k, 1 = q
        const int m = gm & (MROWS - 1);
        const float* raw = which ? qraw : kraw;
        u16* outp = which ? qb : kb;
        const float* g = gamma + (which ? 0 : ZN);
        const float* be = beta + (which ? 0 : ZN);

        float4 x = *(const float4*)(raw + (long long)m * ZN + lane * 4);
        float ss = x.x * x.x + x.y * x.y + x.z * x.z + x.w * x.w;
#pragma unroll
        for (int o = 32; o; o >>= 1) ss += __shfl_down(ss, o, 64);
        const float tot = __shfl(ss, 0, 64);
        const float inv = 1.f / fmaxf(sqrtf(tot), 1e-5f);
        float4 gv = *(const float4*)(g + lane * 4);
        float4 bv = *(const float4*)(be + lane * 4);
        const int b = m & 7, s = m >> 3;
        store_bf16x4(outp + ((long long)b * LN_ + s) * ZN + lane * 4,
                     x.x * inv * (gv.x + 1.f) + bv.x, x.y * inv * (gv.y + 1.f) + bv.y,
                     x.z * inv * (gv.z + 1.f) + bv.z, x.w * inv * (gv.w + 1.f) + bv.w);
    } else {
        const int id2 = id - L2_BLKS;          // [0, 4096)
        const int b  = id2 >> 9;               // 512 tiles per batch
        const int rem = id2 & 511;
        const int e0 = (rem & 15) * 64, c0 = (rem >> 4) * 64;
        const int t  = threadIdx.x;
        const int rc = t >> 3;                 // 0..31
        const int ec = t & 7;                  // 0..7
        const u16* src = vbce + (long long)b * LN_ * EN;
        u16* dst = vT + (long long)b * EN * LN_;
#pragma unroll
        for (int i = 0; i < 64; i += 32) {
            union { uint4 v4; u16 h[8]; } ld;
            ld.v4 = *(const uint4*)(src + (long long)(c0 + rc + i) * EN + (e0 + ec * 8));
#pragma unroll
            for (int j = 0; j < 8; ++j) tile[rc + i][ec * 8 + j] = ld.h[j];
        }
        __syncthreads();
#pragma unroll
        for (int i = 0; i < 64; i += 32) {
            union { uint4 v4; u16 h[8]; } st;
#pragma unroll
            for (int j = 0; j < 8; ++j) st.h[j] = tile[ec * 8 + j][rc + i];
            *(uint4*)(dst + (long long)(e0 + rc + i) * LN_ + (c0 + ec * 8)) = st.v4;
        }
    }
}

// ---------------------------------------------------------------------------
extern "C" void kernel_launch(void* const* d_in, const int* in_sizes, int n_in,
                              void* d_out, int out_size, void* d_ws, size_t ws_size,
                              hipStream_t stream)
{
    const float* query  = (const float*)d_in[0];
    const float* key_in = (const float*)d_in[1];
    const float* value  = (const float*)d_in[2];
    const float* ln_w   = (const float*)d_in[3];
    const float* ln_b   = (const float*)d_in[4];
    const float* Wv     = (const float*)d_in[5];
    const float* bv     = (const float*)d_in[6];
    const float* Wk     = (const float*)d_in[7];
    const float* bk     = (const float*)d_in[8];
    const float* Wqru   = (const float*)d_in[9];
    const float* bqru   = (const float*)d_in[10];
    const float* Wh     = (const float*)d_in[11];
    const float* bh     = (const float*)d_in[12];
    const float* gamma  = (const float*)d_in[13];
    const float* beta   = (const float*)d_in[14];
    const float* relpos = (const float*)d_in[15];
    float* out = (float*)d_out;

    char* ws = (char*)d_ws;
    const size_t MB = 1ull << 20;
    // ---- lifetimes: S1 pre, S2 fused3, S3 post, S4 qk, S5 h, S6 out ----
    // S1->S2:  nq(0-32)  kin(32-64)  valb(64-96)
    // S2->S3:  vbce(96-128) qraw(128-144) kraw(144-160)
    // S2->S6:  ub(160-192)   S2->S5: rb(192-224)
    // S1->S2:  WqruB/WkB/WvB (224-231)   S1->S6: WhB(232-234)
    // S3->S5:  vT(0-32, over dead nq)
    // S3->S4:  qb(32-40) kb(40-48, over dead kin)
    // S4->S5:  attn(48-112, over dead kin/valb/vbce-lo)
    // S5->S6:  hr(112-144, over dead vbce-hi/qraw)
    u16*   nq    = (u16*)(ws + 0);
    u16*   kin   = (u16*)(ws + 32 * MB);
    u16*   valb  = (u16*)(ws + 64 * MB);
    u16*   vbce  = (u16*)(ws + 96 * MB);
    float* qraw  = (float*)(ws + 128 * MB);
    float* kraw  = (float*)(ws + 144 * MB);
    u16*   ub    = (u16*)(ws + 160 * MB);
    u16*   rb    = (u16*)(ws + 192 * MB);
    u16*   WqruB = (u16*)(ws + 224 * MB);   // 4.5 MiB
    u16*   WkB   = (u16*)(ws + 229 * MB);   // 0.5 MiB
    u16*   WvB   = (u16*)(ws + 230 * MB);   // 2 MiB
    u16*   WhB   = (u16*)(ws + 232 * MB);   // 2 MiB
    u16*   vT    = (u16*)(ws + 0);          // 32 MiB
    u16*   qb    = (u16*)(ws + 32 * MB);    // 8 MiB
    u16*   kb    = (u16*)(ws + 40 * MB);    // 8 MiB
    u16*   attn  = (u16*)(ws + 48 * MB);    // 64 MiB
    u16*   hr    = (u16*)(ws + 112 * MB);   // 32 MiB
    (void)ws_size; (void)in_sizes; (void)n_in; (void)out_size;

    // S1) prep + weight casts
    pre_kernel<<<dim3(PREP_BLKS + CAST_BLKS), 256, 0, stream>>>(
        query, key_in, value, ln_w, ln_b, nq, kin, valb,
        Wqru, Wk, Wv, Wh, WqruB, WkB, WvB, WhB);

    // S2) fused qru + k + v GEMMs (all K = 1024)
    gemm_fused3<<<dim3(2304 + 256 + 1024), 256, 0, stream>>>(
        nq, kin, valb, WqruB, WkB, WvB,
        qraw, ub, rb, bqru, kraw, bk, vbce, bv);

    // S3) l2norm (k and q, wave-per-row) + transpose v -> vT
    post_kernel<<<dim3(L2_BLKS + TR_BLKS), 256, 0, stream>>>(
        kraw, qraw, kb, qb, gamma, beta, vbce, vT);

    // S4) attn = relu(q@k^T * scale + bias)^2   (batched over b, K=256)
    gemm_bt<<<dim3(LN_ / 128, LN_ / 128, BN_), 256, 0, stream>>>(
        qb, kb, (long long)LN_ * ZN, (long long)LN_ * ZN, ZN, EpiQK{attn, relpos});

    // S5) hr = (attn @ v) * r   (batched over b, K=2048)
    gemm_bt<<<dim3(EN / 128, LN_ / 128, BN_), 256, 0, stream>>>(
        attn, vT, (long long)LN_ * LN_, (long long)EN * LN_, LN_, EpiH{hr, rb});

    // S6) out = query + u*((hr@Wh^T + bh) - query)
    gemm_bt<<<dim3(EN / 128, MROWS / 128, 1), 256, 0, stream>>>(
        hr, WhB, 0LL, 0LL, EN, EpiOut{out, query, ub, bh});
}